// Round 7
// baseline (118.918 us; speedup 1.0000x reference)
//
#include <hip/hip_runtime.h>
#include <hip/hip_bf16.h>

// Problem constants
#define BB 2
#define HH 56
#define WW 56
#define CC 256
#define HEADS 8
#define HD 32
#define KW 7
#define NPIX (BB*HH*WW)           // 6272
#define KV_N 512

using bf16x8 = __attribute__((ext_vector_type(8))) short;
using f32x4  = __attribute__((ext_vector_type(4))) float;

__device__ __forceinline__ ushort f2bf(float f) {
    union { float f; uint u; } v; v.f = f;
    uint r = v.u + 0x7FFF + ((v.u >> 16) & 1);   // round-to-nearest-even
    return (ushort)(r >> 16);
}
__device__ __forceinline__ float bf2f(ushort h) {
    union { uint u; float f; } v; v.u = ((uint)h) << 16;
    return v.f;
}

// ---- bf16 MFMA GEMM: C[M][N] = A[M][K] @ Wt[N][K]^T + bias[N] ----
// A_BF16: A is already bf16 (direct-copy staging). OUT_BF16: store C as bf16.
template<int BM, int BN, bool A_BF16, bool OUT_BF16>
__global__ __launch_bounds__(256) void gemm_bf16_nt(
    const void* __restrict__ Av, const float* __restrict__ Wt,
    const float* __restrict__ bias, void* __restrict__ Cv,
    int M, int N, int Kd)
{
    constexpr int BK  = 64;
    constexpr int LDT = 72;
    constexpr int WTM = BM / 2, WTN = BN / 2;
    constexpr int MF  = WTM / 16, NF = WTN / 16;

    __shared__ ushort As[BM][LDT];
    __shared__ ushort Bs[BN][LDT];

    const int tid  = threadIdx.x;
    const int lane = tid & 63;
    const int wid  = tid >> 6;
    const int wm   = wid >> 1;
    const int wn   = wid & 1;
    const int bm   = blockIdx.y * BM;
    const int bn   = blockIdx.x * BN;

    const int srow = tid >> 3;
    const int skq  = (tid & 7) * 8;

    f32x4 acc[MF][NF] = {};

    for (int k0 = 0; k0 < Kd; k0 += BK) {
        #pragma unroll
        for (int p = 0; p < BM / 32; ++p) {
            const int r = p * 32 + srow;
            if constexpr (A_BF16) {
                const ushort* src = (const ushort*)Av + (size_t)(bm + r) * Kd + k0 + skq;
                *(bf16x8*)&As[r][skq] = *(const bf16x8*)src;
            } else {
                const float* src = (const float*)Av + (size_t)(bm + r) * Kd + k0 + skq;
                float4 f0 = *(const float4*)(src);
                float4 f1 = *(const float4*)(src + 4);
                bf16x8 v;
                v[0]=f2bf(f0.x); v[1]=f2bf(f0.y); v[2]=f2bf(f0.z); v[3]=f2bf(f0.w);
                v[4]=f2bf(f1.x); v[5]=f2bf(f1.y); v[6]=f2bf(f1.z); v[7]=f2bf(f1.w);
                *(bf16x8*)&As[r][skq] = v;
            }
        }
        #pragma unroll
        for (int p = 0; p < BN / 32; ++p) {
            const int r = p * 32 + srow;
            const float* src = Wt + (size_t)(bn + r) * Kd + k0 + skq;
            float4 f0 = *(const float4*)(src);
            float4 f1 = *(const float4*)(src + 4);
            bf16x8 v;
            v[0]=f2bf(f0.x); v[1]=f2bf(f0.y); v[2]=f2bf(f0.z); v[3]=f2bf(f0.w);
            v[4]=f2bf(f1.x); v[5]=f2bf(f1.y); v[6]=f2bf(f1.z); v[7]=f2bf(f1.w);
            *(bf16x8*)&Bs[r][skq] = v;
        }
        __syncthreads();

        #pragma unroll
        for (int ks = 0; ks < 2; ++ks) {
            const int koff = ks * 32 + (lane >> 4) * 8;
            bf16x8 af[MF], bf[NF];
            #pragma unroll
            for (int m = 0; m < MF; ++m)
                af[m] = *(const bf16x8*)&As[wm*WTM + m*16 + (lane & 15)][koff];
            #pragma unroll
            for (int n = 0; n < NF; ++n)
                bf[n] = *(const bf16x8*)&Bs[wn*WTN + n*16 + (lane & 15)][koff];
            #pragma unroll
            for (int m = 0; m < MF; ++m)
                #pragma unroll
                for (int n = 0; n < NF; ++n)
                    acc[m][n] = __builtin_amdgcn_mfma_f32_16x16x32_bf16(af[m], bf[n], acc[m][n], 0, 0, 0);
        }
        __syncthreads();
    }

    #pragma unroll
    for (int n = 0; n < NF; ++n) {
        const int col = bn + wn*WTN + n*16 + (lane & 15);
        const float bval = bias[col];
        #pragma unroll
        for (int m = 0; m < MF; ++m) {
            const int row0 = bm + wm*WTM + m*16 + (lane >> 4) * 4;
            #pragma unroll
            for (int r = 0; r < 4; ++r) {
                const float o = acc[m][n][r] + bval;
                if constexpr (OUT_BF16)
                    ((ushort*)Cv)[(size_t)(row0 + r) * N + col] = f2bf(o);
                else
                    ((float*)Cv)[(size_t)(row0 + r) * N + col] = o;
            }
        }
    }
}

// ---- Neighborhood attention, LDS-tiled, bf16 LDS ----
// Block = (batch, 8x8 pixel tile, head). Stage 14x14 K/V window as bf16
// (stride 40 bf16 = 80B; <=2-way bank alias = free). Thread = (pixel, 8-dim
// sub): one ds_read_b128 per (score,sub) for K and one for V (halved vs f32
// LDS); bf16->f32 cvt is exact shifts on the idle VALU pipe. Inner control
// flow identical to the verified round-5/6 structure; all compile-time
// indexed (rule #20).
__global__ __launch_bounds__(256) void natt_tile(
    const float* __restrict__ q_extra, const ushort* __restrict__ kv,
    const float* __restrict__ rpb, ushort* __restrict__ attn_out)
{
    constexpr int LSTR = 40;           // bf16 elems per pixel row in LDS
    __shared__ ushort Ks[196 * LSTR];  // 15.7 KB
    __shared__ ushort Vs[196 * LSTR];  // 15.7 KB

    const int blk  = blockIdx.x;
    const int head = blk & 7;
    const int t    = blk >> 3;          // 0..97
    const int tj   = t % 7;
    const int ti   = (t / 7) % 7;
    const int b    = t / 49;

    const int r0 = max(0, ti * 8 - 3);
    const int c0 = max(0, tj * 8 - 3);

    const int tid = threadIdx.x;

    // stage: e -> (pixel, half(K/V), 8-dim chunk); direct bf16x8 copy
    for (int e = tid; e < 196 * 8; e += 256) {
        const int spix  = e >> 3;
        const int f4    = e & 7;
        const int half  = f4 >> 2;           // 0 = K, 1 = V
        const int chunk = f4 & 3;            // 8-dim chunk
        const int wr   = spix / 14;
        const int wc   = spix - wr * 14;
        const int gr   = min(r0 + wr, HH - 1);
        const int gc   = min(c0 + wc, WW - 1);
        const ushort* src = kv + ((size_t)((b * HH + gr) * WW + gc)) * KV_N
                               + half * CC + head * HD + chunk * 8;
        ushort* dst = (half ? Vs : Ks) + spix * LSTR + chunk * 8;
        *(bf16x8*)dst = *(const bf16x8*)src;
    }

    const int sub = tid & 3;
    const int p   = tid >> 2;           // 0..63
    const int li  = p >> 3, lj = p & 7;
    const int i = ti * 8 + li, j = tj * 8 + lj;
    const int pix = (b * HH + i) * WW + j;
    const int d0 = sub * 8;

    const float scale = 0.17677669529663687f;  // 32^-0.5
    float q[8];
    {
        const float* qp = q_extra + (size_t)pix * CC + head * HD + d0;
        float4 v0 = *(const float4*)(qp);
        float4 v1 = *(const float4*)(qp + 4);
        q[0]=v0.x*scale; q[1]=v0.y*scale; q[2]=v0.z*scale; q[3]=v0.w*scale;
        q[4]=v1.x*scale; q[5]=v1.y*scale; q[6]=v1.z*scale; q[7]=v1.w*scale;
    }

    const int sh = min(max(i - 3, 0), HH - KW);
    const int sw = min(max(j - 3, 0), WW - KW);
    const int wr0 = sh - r0;            // 0..7
    const int wc0 = sw - c0;            // 0..7
    const int pbi0 = sh - i + 6;
    const int pbj0 = sw - j + 6;

    __syncthreads();

    // QK + bias, quad-reduced; scores in registers
    float s[49];
    float mmax = -3.4e38f;
    #pragma unroll
    for (int a = 0; a < KW; ++a) {
        const ushort* kr = &Ks[((wr0 + a) * 14 + wc0) * LSTR + d0];
        const float* bp = rpb + (size_t)head * 169 + (size_t)(pbi0 + a) * 13 + pbj0;
        #pragma unroll
        for (int c = 0; c < KW; ++c) {
            bf16x8 kk = *(const bf16x8*)(kr + c * LSTR);
            float v = q[0]*bf2f((ushort)kk[0]) + q[1]*bf2f((ushort)kk[1])
                    + q[2]*bf2f((ushort)kk[2]) + q[3]*bf2f((ushort)kk[3])
                    + q[4]*bf2f((ushort)kk[4]) + q[5]*bf2f((ushort)kk[5])
                    + q[6]*bf2f((ushort)kk[6]) + q[7]*bf2f((ushort)kk[7]);
            v += __shfl_xor(v, 1);
            v += __shfl_xor(v, 2);
            v += bp[c];
            s[a * KW + c] = v;
            mmax = fmaxf(mmax, v);
        }
    }

    float sum = 0.f;
    #pragma unroll
    for (int k = 0; k < KW * KW; ++k) {
        s[k] = __expf(s[k] - mmax);
        sum += s[k];
    }
    const float inv = 1.0f / sum;

    // PV from LDS
    float acc[8] = {};
    #pragma unroll
    for (int a = 0; a < KW; ++a) {
        const ushort* vr = &Vs[((wr0 + a) * 14 + wc0) * LSTR + d0];
        #pragma unroll
        for (int c = 0; c < KW; ++c) {
            bf16x8 vv = *(const bf16x8*)(vr + c * LSTR);
            const float w = s[a * KW + c];
            acc[0] += w*bf2f((ushort)vv[0]); acc[1] += w*bf2f((ushort)vv[1]);
            acc[2] += w*bf2f((ushort)vv[2]); acc[3] += w*bf2f((ushort)vv[3]);
            acc[4] += w*bf2f((ushort)vv[4]); acc[5] += w*bf2f((ushort)vv[5]);
            acc[6] += w*bf2f((ushort)vv[6]); acc[7] += w*bf2f((ushort)vv[7]);
        }
    }

    ushort* op = attn_out + (size_t)pix * CC + head * HD + d0;
    bf16x8 o;
    o[0]=f2bf(acc[0]*inv); o[1]=f2bf(acc[1]*inv);
    o[2]=f2bf(acc[2]*inv); o[3]=f2bf(acc[3]*inv);
    o[4]=f2bf(acc[4]*inv); o[5]=f2bf(acc[5]*inv);
    o[6]=f2bf(acc[6]*inv); o[7]=f2bf(acc[7]*inv);
    *(bf16x8*)op = o;
}

extern "C" void kernel_launch(void* const* d_in, const int* in_sizes, int n_in,
                              void* d_out, int out_size, void* d_ws, size_t ws_size,
                              hipStream_t stream) {
    const float* x       = (const float*)d_in[0];
    const float* q_extra = (const float*)d_in[1];
    const float* kv_w    = (const float*)d_in[2];
    const float* kv_b    = (const float*)d_in[3];
    const float* rpb     = (const float*)d_in[4];
    const float* proj_w  = (const float*)d_in[5];
    const float* proj_b  = (const float*)d_in[6];
    float* out = (float*)d_out;

    ushort* kv       = (ushort*)d_ws;                      // NPIX*512 bf16 = 6.4 MB
    ushort* attn_out = kv + (size_t)NPIX * KV_N;           // NPIX*256 bf16 = 3.2 MB

    // 1) kv = bf16( x @ kv_w^T + kv_b )   (M=6272, N=512, K=256), 64x64 tiles
    {
        dim3 grid(KV_N/64, NPIX/64);
        gemm_bf16_nt<64,64,false,true><<<grid, 256, 0, stream>>>(x, kv_w, kv_b, kv, NPIX, KV_N, CC);
    }
    // 2) neighborhood attention (bf16 LDS, f32 compute)
    {
        dim3 grid(BB * 49 * HEADS);
        natt_tile<<<grid, 256, 0, stream>>>(q_extra, kv, rpb, attn_out);
    }
    // 3) out = attn_out(bf16) @ proj_w^T + proj_b   (M=6272, N=256, K=256)
    {
        dim3 grid(CC/64, NPIX/64);
        gemm_bf16_nt<64,64,true,false><<<grid, 256, 0, stream>>>(attn_out, proj_w, proj_b, out, NPIX, CC, CC);
    }
}

// Round 9
// 113.994 us; speedup vs baseline: 1.0432x; 1.0432x over previous
//
#include <hip/hip_runtime.h>
#include <hip/hip_bf16.h>

// Problem constants
#define BB 2
#define HH 56
#define WW 56
#define CC 256
#define HEADS 8
#define HD 32
#define KW 7
#define NPIX (BB*HH*WW)           // 6272
#define KV_N 512

using bf16x8 = __attribute__((ext_vector_type(8))) short;
using f32x4  = __attribute__((ext_vector_type(4))) float;

__device__ __forceinline__ ushort f2bf(float f) {
    union { float f; uint u; } v; v.f = f;
    uint r = v.u + 0x7FFF + ((v.u >> 16) & 1);   // round-to-nearest-even
    return (ushort)(r >> 16);
}
__device__ __forceinline__ float bf2f(ushort h) {
    union { uint u; float f; } v; v.u = ((uint)h) << 16;
    return v.f;
}
// quad butterfly add via DPP (pure VALU, no LDS pipe).
// CTRL: 0xB1 = quad_perm xor1, 0x4E = quad_perm xor2. Must be compile-time.
template<int CTRL>
__device__ __forceinline__ float dpp_qadd(float v) {
    union { float f; int i; } a, b;
    a.f = v;
    b.i = __builtin_amdgcn_update_dpp(0, a.i, CTRL, 0xF, 0xF, true);
    return v + b.f;
}

// ---- bf16 MFMA GEMM: C[M][N] = A[M][K] @ Wt[N][K]^T + bias[N] ----
// (frozen since round 6)
template<int BM, int BN, bool A_BF16, bool OUT_BF16>
__global__ __launch_bounds__(256) void gemm_bf16_nt(
    const void* __restrict__ Av, const float* __restrict__ Wt,
    const float* __restrict__ bias, void* __restrict__ Cv,
    int M, int N, int Kd)
{
    constexpr int BK  = 64;
    constexpr int LDT = 72;
    constexpr int WTM = BM / 2, WTN = BN / 2;
    constexpr int MF  = WTM / 16, NF = WTN / 16;

    __shared__ ushort As[BM][LDT];
    __shared__ ushort Bs[BN][LDT];

    const int tid  = threadIdx.x;
    const int lane = tid & 63;
    const int wid  = tid >> 6;
    const int wm   = wid >> 1;
    const int wn   = wid & 1;
    const int bm   = blockIdx.y * BM;
    const int bn   = blockIdx.x * BN;

    const int srow = tid >> 3;
    const int skq  = (tid & 7) * 8;

    f32x4 acc[MF][NF] = {};

    for (int k0 = 0; k0 < Kd; k0 += BK) {
        #pragma unroll
        for (int p = 0; p < BM / 32; ++p) {
            const int r = p * 32 + srow;
            if constexpr (A_BF16) {
                const ushort* src = (const ushort*)Av + (size_t)(bm + r) * Kd + k0 + skq;
                *(bf16x8*)&As[r][skq] = *(const bf16x8*)src;
            } else {
                const float* src = (const float*)Av + (size_t)(bm + r) * Kd + k0 + skq;
                float4 f0 = *(const float4*)(src);
                float4 f1 = *(const float4*)(src + 4);
                bf16x8 v;
                v[0]=f2bf(f0.x); v[1]=f2bf(f0.y); v[2]=f2bf(f0.z); v[3]=f2bf(f0.w);
                v[4]=f2bf(f1.x); v[5]=f2bf(f1.y); v[6]=f2bf(f1.z); v[7]=f2bf(f1.w);
                *(bf16x8*)&As[r][skq] = v;
            }
        }
        #pragma unroll
        for (int p = 0; p < BN / 32; ++p) {
            const int r = p * 32 + srow;
            const float* src = Wt + (size_t)(bn + r) * Kd + k0 + skq;
            float4 f0 = *(const float4*)(src);
            float4 f1 = *(const float4*)(src + 4);
            bf16x8 v;
            v[0]=f2bf(f0.x); v[1]=f2bf(f0.y); v[2]=f2bf(f0.z); v[3]=f2bf(f0.w);
            v[4]=f2bf(f1.x); v[5]=f2bf(f1.y); v[6]=f2bf(f1.z); v[7]=f2bf(f1.w);
            *(bf16x8*)&Bs[r][skq] = v;
        }
        __syncthreads();

        #pragma unroll
        for (int ks = 0; ks < 2; ++ks) {
            const int koff = ks * 32 + (lane >> 4) * 8;
            bf16x8 af[MF], bf[NF];
            #pragma unroll
            for (int m = 0; m < MF; ++m)
                af[m] = *(const bf16x8*)&As[wm*WTM + m*16 + (lane & 15)][koff];
            #pragma unroll
            for (int n = 0; n < NF; ++n)
                bf[n] = *(const bf16x8*)&Bs[wn*WTN + n*16 + (lane & 15)][koff];
            #pragma unroll
            for (int m = 0; m < MF; ++m)
                #pragma unroll
                for (int n = 0; n < NF; ++n)
                    acc[m][n] = __builtin_amdgcn_mfma_f32_16x16x32_bf16(af[m], bf[n], acc[m][n], 0, 0, 0);
        }
        __syncthreads();
    }

    #pragma unroll
    for (int n = 0; n < NF; ++n) {
        const int col = bn + wn*WTN + n*16 + (lane & 15);
        const float bval = bias[col];
        #pragma unroll
        for (int m = 0; m < MF; ++m) {
            const int row0 = bm + wm*WTM + m*16 + (lane >> 4) * 4;
            #pragma unroll
            for (int r = 0; r < 4; ++r) {
                const float o = acc[m][n][r] + bval;
                if constexpr (OUT_BF16)
                    ((ushort*)Cv)[(size_t)(row0 + r) * N + col] = f2bf(o);
                else
                    ((float*)Cv)[(size_t)(row0 + r) * N + col] = o;
            }
        }
    }
}

// ---- Neighborhood attention, LDS-tiled, bf16 LDS, 8x4 tiles ----
// Block = (batch, 8x4 pixel tile, head), 128 threads, grid 1568 (6.1/CU).
// Stage 14x10 K/V window (bf16, stride 40 = 80B) + rpb head-slice in LDS.
// Thread = (pixel, 8-dim sub); quad-reduce via DPP (VALU, no LDS pipe).
// All register arrays compile-time indexed (rule #20).
#define TI_H 8
#define TJ_W 4
#define WIN_R 14
#define WIN_C 10
#define NWPIX (WIN_R*WIN_C)   // 140
#define LSTR 40
__global__ __launch_bounds__(128) void natt_tile(
    const float* __restrict__ q_extra, const ushort* __restrict__ kv,
    const float* __restrict__ rpb, ushort* __restrict__ attn_out)
{
    __shared__ ushort Ks[NWPIX * LSTR];   // 11.2 KB
    __shared__ ushort Vs[NWPIX * LSTR];   // 11.2 KB
    __shared__ float  Bias[169];

    const int blk  = blockIdx.x;
    const int head = blk & 7;
    const int t    = blk >> 3;          // 0..195
    const int tj   = t % 14;
    const int ti   = (t / 14) % 7;
    const int b    = t / 98;

    const int r0 = max(0, ti * TI_H - 3);
    const int c0 = max(0, tj * TJ_W - 3);

    const int tid = threadIdx.x;

    // stage rpb head-slice (169 f32)
    for (int e = tid; e < 169; e += 128)
        Bias[e] = rpb[head * 169 + e];

    // stage K/V: e -> (window pixel, half(K/V), 8-dim chunk); direct bf16x8 copy
    for (int e = tid; e < NWPIX * 8; e += 128) {
        const int spix  = e >> 3;
        const int f4    = e & 7;
        const int half  = f4 >> 2;
        const int chunk = f4 & 3;
        const int wr   = spix / WIN_C;
        const int wc   = spix - wr * WIN_C;
        const int gr   = min(r0 + wr, HH - 1);
        const int gc   = min(c0 + wc, WW - 1);
        const ushort* src = kv + ((size_t)((b * HH + gr) * WW + gc)) * KV_N
                               + half * CC + head * HD + chunk * 8;
        ushort* dst = (half ? Vs : Ks) + spix * LSTR + chunk * 8;
        *(bf16x8*)dst = *(const bf16x8*)src;
    }

    const int sub = tid & 3;
    const int p   = tid >> 2;           // 0..31
    const int li  = p >> 2, lj = p & 3;
    const int i = ti * TI_H + li, j = tj * TJ_W + lj;
    const int pix = (b * HH + i) * WW + j;
    const int d0 = sub * 8;

    const float scale = 0.17677669529663687f;  // 32^-0.5
    float q[8];
    {
        const float* qp = q_extra + (size_t)pix * CC + head * HD + d0;
        float4 v0 = *(const float4*)(qp);
        float4 v1 = *(const float4*)(qp + 4);
        q[0]=v0.x*scale; q[1]=v0.y*scale; q[2]=v0.z*scale; q[3]=v0.w*scale;
        q[4]=v1.x*scale; q[5]=v1.y*scale; q[6]=v1.z*scale; q[7]=v1.w*scale;
    }

    const int sh = min(max(i - 3, 0), HH - KW);
    const int sw = min(max(j - 3, 0), WW - KW);
    const int wr0 = sh - r0;            // 0..7
    const int wc0 = sw - c0;            // 0..3
    const int pbi0 = sh - i + 6;
    const int pbj0 = sw - j + 6;

    __syncthreads();

    // QK + bias, quad-reduced via DPP; scores in registers
    float s[49];
    float mmax = -3.4e38f;
    #pragma unroll
    for (int a = 0; a < KW; ++a) {
        const ushort* kr = &Ks[((wr0 + a) * WIN_C + wc0) * LSTR + d0];
        const float* bp = &Bias[(pbi0 + a) * 13 + pbj0];
        #pragma unroll
        for (int c = 0; c < KW; ++c) {
            bf16x8 kk = *(const bf16x8*)(kr + c * LSTR);
            float v = q[0]*bf2f((ushort)kk[0]) + q[1]*bf2f((ushort)kk[1])
                    + q[2]*bf2f((ushort)kk[2]) + q[3]*bf2f((ushort)kk[3])
                    + q[4]*bf2f((ushort)kk[4]) + q[5]*bf2f((ushort)kk[5])
                    + q[6]*bf2f((ushort)kk[6]) + q[7]*bf2f((ushort)kk[7]);
            v = dpp_qadd<0xB1>(v);      // quad_perm xor 1
            v = dpp_qadd<0x4E>(v);      // quad_perm xor 2
            v += bp[c];
            s[a * KW + c] = v;
            mmax = fmaxf(mmax, v);
        }
    }

    float sum = 0.f;
    #pragma unroll
    for (int k = 0; k < KW * KW; ++k) {
        s[k] = __expf(s[k] - mmax);
        sum += s[k];
    }
    const float inv = 1.0f / sum;

    // PV from LDS
    float acc[8] = {};
    #pragma unroll
    for (int a = 0; a < KW; ++a) {
        const ushort* vr = &Vs[((wr0 + a) * WIN_C + wc0) * LSTR + d0];
        #pragma unroll
        for (int c = 0; c < KW; ++c) {
            bf16x8 vv = *(const bf16x8*)(vr + c * LSTR);
            const float w = s[a * KW + c];
            acc[0] += w*bf2f((ushort)vv[0]); acc[1] += w*bf2f((ushort)vv[1]);
            acc[2] += w*bf2f((ushort)vv[2]); acc[3] += w*bf2f((ushort)vv[3]);
            acc[4] += w*bf2f((ushort)vv[4]); acc[5] += w*bf2f((ushort)vv[5]);
            acc[6] += w*bf2f((ushort)vv[6]); acc[7] += w*bf2f((ushort)vv[7]);
        }
    }

    ushort* op = attn_out + (size_t)pix * CC + head * HD + d0;
    bf16x8 o;
    o[0]=f2bf(acc[0]*inv); o[1]=f2bf(acc[1]*inv);
    o[2]=f2bf(acc[2]*inv); o[3]=f2bf(acc[3]*inv);
    o[4]=f2bf(acc[4]*inv); o[5]=f2bf(acc[5]*inv);
    o[6]=f2bf(acc[6]*inv); o[7]=f2bf(acc[7]*inv);
    *(bf16x8*)op = o;
}

extern "C" void kernel_launch(void* const* d_in, const int* in_sizes, int n_in,
                              void* d_out, int out_size, void* d_ws, size_t ws_size,
                              hipStream_t stream) {
    const float* x       = (const float*)d_in[0];
    const float* q_extra = (const float*)d_in[1];
    const float* kv_w    = (const float*)d_in[2];
    const float* kv_b    = (const float*)d_in[3];
    const float* rpb     = (const float*)d_in[4];
    const float* proj_w  = (const float*)d_in[5];
    const float* proj_b  = (const float*)d_in[6];
    float* out = (float*)d_out;

    ushort* kv       = (ushort*)d_ws;                      // NPIX*512 bf16 = 6.4 MB
    ushort* attn_out = kv + (size_t)NPIX * KV_N;           // NPIX*256 bf16 = 3.2 MB

    // 1) kv = bf16( x @ kv_w^T + kv_b )   (M=6272, N=512, K=256)
    {
        dim3 grid(KV_N/64, NPIX/64);
        gemm_bf16_nt<64,64,false,true><<<grid, 256, 0, stream>>>(x, kv_w, kv_b, kv, NPIX, KV_N, CC);
    }
    // 2) neighborhood attention (8x4 tiles, 1568 blocks, 128 threads)
    {
        dim3 grid(BB * 7 * 14 * HEADS);
        natt_tile<<<grid, 128, 0, stream>>>(q_extra, kv, rpb, attn_out);
    }
    // 3) out = attn_out(bf16) @ proj_w^T + proj_b   (M=6272, N=256, K=256)
    {
        dim3 grid(CC/64, NPIX/64);
        gemm_bf16_nt<64,64,true,false><<<grid, 256, 0, stream>>>(attn_out, proj_w, proj_b, out, NPIX, CC, CC);
    }
}

// Round 10
// 111.812 us; speedup vs baseline: 1.0636x; 1.0195x over previous
//
#include <hip/hip_runtime.h>
#include <hip/hip_bf16.h>

// Problem constants
#define BB 2
#define HH 56
#define WW 56
#define CC 256
#define HEADS 8
#define HD 32
#define KW 7
#define NPIX (BB*HH*WW)           // 6272
#define KV_N 512

using bf16x8 = __attribute__((ext_vector_type(8))) short;
using f32x4  = __attribute__((ext_vector_type(4))) float;

__device__ __forceinline__ ushort f2bf(float f) {
    union { float f; uint u; } v; v.f = f;
    uint r = v.u + 0x7FFF + ((v.u >> 16) & 1);   // round-to-nearest-even
    return (ushort)(r >> 16);
}
__device__ __forceinline__ float bf2f(ushort h) {
    union { uint u; float f; } v; v.u = ((uint)h) << 16;
    return v.f;
}
// quad butterfly add via DPP (pure VALU, no LDS pipe).
// CTRL: 0xB1 = quad_perm xor1, 0x4E = quad_perm xor2. Must be compile-time.
template<int CTRL>
__device__ __forceinline__ float dpp_qadd(float v) {
    union { float f; int i; } a, b;
    a.f = v;
    b.i = __builtin_amdgcn_update_dpp(0, a.i, CTRL, 0xF, 0xF, true);
    return v + b.f;
}

// ---- bf16 MFMA GEMM: C[M][N] = A[M][K] @ Wt[N][K]^T + bias[N] ----
// (frozen since round 6)
template<int BM, int BN, bool A_BF16, bool OUT_BF16>
__global__ __launch_bounds__(256) void gemm_bf16_nt(
    const void* __restrict__ Av, const float* __restrict__ Wt,
    const float* __restrict__ bias, void* __restrict__ Cv,
    int M, int N, int Kd)
{
    constexpr int BK  = 64;
    constexpr int LDT = 72;
    constexpr int WTM = BM / 2, WTN = BN / 2;
    constexpr int MF  = WTM / 16, NF = WTN / 16;

    __shared__ ushort As[BM][LDT];
    __shared__ ushort Bs[BN][LDT];

    const int tid  = threadIdx.x;
    const int lane = tid & 63;
    const int wid  = tid >> 6;
    const int wm   = wid >> 1;
    const int wn   = wid & 1;
    const int bm   = blockIdx.y * BM;
    const int bn   = blockIdx.x * BN;

    const int srow = tid >> 3;
    const int skq  = (tid & 7) * 8;

    f32x4 acc[MF][NF] = {};

    for (int k0 = 0; k0 < Kd; k0 += BK) {
        #pragma unroll
        for (int p = 0; p < BM / 32; ++p) {
            const int r = p * 32 + srow;
            if constexpr (A_BF16) {
                const ushort* src = (const ushort*)Av + (size_t)(bm + r) * Kd + k0 + skq;
                *(bf16x8*)&As[r][skq] = *(const bf16x8*)src;
            } else {
                const float* src = (const float*)Av + (size_t)(bm + r) * Kd + k0 + skq;
                float4 f0 = *(const float4*)(src);
                float4 f1 = *(const float4*)(src + 4);
                bf16x8 v;
                v[0]=f2bf(f0.x); v[1]=f2bf(f0.y); v[2]=f2bf(f0.z); v[3]=f2bf(f0.w);
                v[4]=f2bf(f1.x); v[5]=f2bf(f1.y); v[6]=f2bf(f1.z); v[7]=f2bf(f1.w);
                *(bf16x8*)&As[r][skq] = v;
            }
        }
        #pragma unroll
        for (int p = 0; p < BN / 32; ++p) {
            const int r = p * 32 + srow;
            const float* src = Wt + (size_t)(bn + r) * Kd + k0 + skq;
            float4 f0 = *(const float4*)(src);
            float4 f1 = *(const float4*)(src + 4);
            bf16x8 v;
            v[0]=f2bf(f0.x); v[1]=f2bf(f0.y); v[2]=f2bf(f0.z); v[3]=f2bf(f0.w);
            v[4]=f2bf(f1.x); v[5]=f2bf(f1.y); v[6]=f2bf(f1.z); v[7]=f2bf(f1.w);
            *(bf16x8*)&Bs[r][skq] = v;
        }
        __syncthreads();

        #pragma unroll
        for (int ks = 0; ks < 2; ++ks) {
            const int koff = ks * 32 + (lane >> 4) * 8;
            bf16x8 af[MF], bf[NF];
            #pragma unroll
            for (int m = 0; m < MF; ++m)
                af[m] = *(const bf16x8*)&As[wm*WTM + m*16 + (lane & 15)][koff];
            #pragma unroll
            for (int n = 0; n < NF; ++n)
                bf[n] = *(const bf16x8*)&Bs[wn*WTN + n*16 + (lane & 15)][koff];
            #pragma unroll
            for (int m = 0; m < MF; ++m)
                #pragma unroll
                for (int n = 0; n < NF; ++n)
                    acc[m][n] = __builtin_amdgcn_mfma_f32_16x16x32_bf16(af[m], bf[n], acc[m][n], 0, 0, 0);
        }
        __syncthreads();
    }

    #pragma unroll
    for (int n = 0; n < NF; ++n) {
        const int col = bn + wn*WTN + n*16 + (lane & 15);
        const float bval = bias[col];
        #pragma unroll
        for (int m = 0; m < MF; ++m) {
            const int row0 = bm + wm*WTM + m*16 + (lane >> 4) * 4;
            #pragma unroll
            for (int r = 0; r < 4; ++r) {
                const float o = acc[m][n][r] + bval;
                if constexpr (OUT_BF16)
                    ((ushort*)Cv)[(size_t)(row0 + r) * N + col] = f2bf(o);
                else
                    ((float*)Cv)[(size_t)(row0 + r) * N + col] = o;
            }
        }
    }
}

// ---- Neighborhood attention, LDS-tiled, bf16 LDS, 8x4 tiles, row-split ----
// Block = (batch, 8x4 pixel tile, head), 256 threads (4 waves), grid 1568.
// Thread = (pixel, 8-dim sub, row-half): half 0 -> window rows 0-3,
// half 1 -> rows 4-6 padded to 4 via clamped row + -inf scores (uniform, no
// divergence, exp->0, PV weight->0). Cross-half combine via __shfl_xor(,4).
// Quad DPP reduce unchanged (quad = same half). Rule #20: all reg arrays
// compile-time indexed.
#define TI_H 8
#define TJ_W 4
#define WIN_R 14
#define WIN_C 10
#define NWPIX (WIN_R*WIN_C)   // 140
#define LSTR 40
__global__ __launch_bounds__(256) void natt_tile(
    const float* __restrict__ q_extra, const ushort* __restrict__ kv,
    const float* __restrict__ rpb, ushort* __restrict__ attn_out)
{
    __shared__ ushort Ks[NWPIX * LSTR];   // 11.2 KB
    __shared__ ushort Vs[NWPIX * LSTR];   // 11.2 KB
    __shared__ float  Bias[169];

    const int blk  = blockIdx.x;
    const int head = blk & 7;
    const int t    = blk >> 3;          // 0..195
    const int tj   = t % 14;
    const int ti   = (t / 14) % 7;
    const int b    = t / 98;

    const int r0 = max(0, ti * TI_H - 3);
    const int c0 = max(0, tj * TJ_W - 3);

    const int tid = threadIdx.x;

    // stage rpb head-slice (169 f32)
    for (int e = tid; e < 169; e += 256)
        Bias[e] = rpb[head * 169 + e];

    // stage K/V: e -> (window pixel, half(K/V), 8-dim chunk); direct bf16x8 copy
    for (int e = tid; e < NWPIX * 8; e += 256) {
        const int spix  = e >> 3;
        const int f4    = e & 7;
        const int kvh   = f4 >> 2;
        const int chunk = f4 & 3;
        const int wr   = spix / WIN_C;
        const int wc   = spix - wr * WIN_C;
        const int gr   = min(r0 + wr, HH - 1);
        const int gc   = min(c0 + wc, WW - 1);
        const ushort* src = kv + ((size_t)((b * HH + gr) * WW + gc)) * KV_N
                               + kvh * CC + head * HD + chunk * 8;
        ushort* dst = (kvh ? Vs : Ks) + spix * LSTR + chunk * 8;
        *(bf16x8*)dst = *(const bf16x8*)src;
    }

    const int sub  = tid & 3;
    const int half = (tid >> 2) & 1;
    const int p    = tid >> 3;          // 0..31
    const int li   = p >> 2, lj = p & 3;
    const int i = ti * TI_H + li, j = tj * TJ_W + lj;
    const int pix = (b * HH + i) * WW + j;
    const int d0 = sub * 8;

    const float scale = 0.17677669529663687f;  // 32^-0.5
    float q[8];
    {
        const float* qp = q_extra + (size_t)pix * CC + head * HD + d0;
        float4 v0 = *(const float4*)(qp);
        float4 v1 = *(const float4*)(qp + 4);
        q[0]=v0.x*scale; q[1]=v0.y*scale; q[2]=v0.z*scale; q[3]=v0.w*scale;
        q[4]=v1.x*scale; q[5]=v1.y*scale; q[6]=v1.z*scale; q[7]=v1.w*scale;
    }

    const int sh = min(max(i - 3, 0), HH - KW);
    const int sw = min(max(j - 3, 0), WW - KW);
    const int wr0 = sh - r0;            // 0..7
    const int wc0 = sw - c0;            // 0..3
    const int pbi0 = sh - i + 6;
    const int pbj0 = sw - j + 6;

    __syncthreads();

    // QK + bias over this half's 4 (padded) rows; quad-DPP reduce; uniform flow
    float s[28];
    float mmax = -3.4e38f;
    #pragma unroll
    for (int r = 0; r < 4; ++r) {
        const int a = min(half * 4 + r, 6);          // h1 r3 clamps to row 6
        const bool live = (half == 0) || (r < 3);    // h1 r3 is a phantom
        const ushort* kr = &Ks[((wr0 + a) * WIN_C + wc0) * LSTR + d0];
        const float* bp = &Bias[(pbi0 + a) * 13 + pbj0];
        #pragma unroll
        for (int c = 0; c < KW; ++c) {
            bf16x8 kk = *(const bf16x8*)(kr + c * LSTR);
            float v = q[0]*bf2f((ushort)kk[0]) + q[1]*bf2f((ushort)kk[1])
                    + q[2]*bf2f((ushort)kk[2]) + q[3]*bf2f((ushort)kk[3])
                    + q[4]*bf2f((ushort)kk[4]) + q[5]*bf2f((ushort)kk[5])
                    + q[6]*bf2f((ushort)kk[6]) + q[7]*bf2f((ushort)kk[7]);
            v = dpp_qadd<0xB1>(v);      // quad_perm xor 1
            v = dpp_qadd<0x4E>(v);      // quad_perm xor 2
            v += bp[c];
            v = live ? v : -3.4e38f;
            s[r * KW + c] = v;
            mmax = fmaxf(mmax, v);
        }
    }
    mmax = fmaxf(mmax, __shfl_xor(mmax, 4));

    float sum = 0.f;
    #pragma unroll
    for (int k = 0; k < 28; ++k) {
        s[k] = __expf(s[k] - mmax);
        sum += s[k];
    }
    sum += __shfl_xor(sum, 4);
    const float inv = 1.0f / sum;

    // PV over this half's rows (phantom row has zero weights)
    float acc[8] = {};
    #pragma unroll
    for (int r = 0; r < 4; ++r) {
        const int a = min(half * 4 + r, 6);
        const ushort* vr = &Vs[((wr0 + a) * WIN_C + wc0) * LSTR + d0];
        #pragma unroll
        for (int c = 0; c < KW; ++c) {
            bf16x8 vv = *(const bf16x8*)(vr + c * LSTR);
            const float w = s[r * KW + c];
            acc[0] += w*bf2f((ushort)vv[0]); acc[1] += w*bf2f((ushort)vv[1]);
            acc[2] += w*bf2f((ushort)vv[2]); acc[3] += w*bf2f((ushort)vv[3]);
            acc[4] += w*bf2f((ushort)vv[4]); acc[5] += w*bf2f((ushort)vv[5]);
            acc[6] += w*bf2f((ushort)vv[6]); acc[7] += w*bf2f((ushort)vv[7]);
        }
    }
    #pragma unroll
    for (int d = 0; d < 8; ++d)
        acc[d] += __shfl_xor(acc[d], 4);

    if (half == 0) {
        ushort* op = attn_out + (size_t)pix * CC + head * HD + d0;
        bf16x8 o;
        o[0]=f2bf(acc[0]*inv); o[1]=f2bf(acc[1]*inv);
        o[2]=f2bf(acc[2]*inv); o[3]=f2bf(acc[3]*inv);
        o[4]=f2bf(acc[4]*inv); o[5]=f2bf(acc[5]*inv);
        o[6]=f2bf(acc[6]*inv); o[7]=f2bf(acc[7]*inv);
        *(bf16x8*)op = o;
    }
}

extern "C" void kernel_launch(void* const* d_in, const int* in_sizes, int n_in,
                              void* d_out, int out_size, void* d_ws, size_t ws_size,
                              hipStream_t stream) {
    const float* x       = (const float*)d_in[0];
    const float* q_extra = (const float*)d_in[1];
    const float* kv_w    = (const float*)d_in[2];
    const float* kv_b    = (const float*)d_in[3];
    const float* rpb     = (const float*)d_in[4];
    const float* proj_w  = (const float*)d_in[5];
    const float* proj_b  = (const float*)d_in[6];
    float* out = (float*)d_out;

    ushort* kv       = (ushort*)d_ws;                      // NPIX*512 bf16 = 6.4 MB
    ushort* attn_out = kv + (size_t)NPIX * KV_N;           // NPIX*256 bf16 = 3.2 MB

    // 1) kv = bf16( x @ kv_w^T + kv_b )   (M=6272, N=512, K=256)
    {
        dim3 grid(KV_N/64, NPIX/64);
        gemm_bf16_nt<64,64,false,true><<<grid, 256, 0, stream>>>(x, kv_w, kv_b, kv, NPIX, KV_N, CC);
    }
    // 2) neighborhood attention (8x4 tiles, 1568 blocks, 256 threads, row-split)
    {
        dim3 grid(BB * 7 * 14 * HEADS);
        natt_tile<<<grid, 256, 0, stream>>>(q_extra, kv, rpb, attn_out);
    }
    // 3) out = attn_out(bf16) @ proj_w^T + proj_b   (M=6272, N=256, K=256)
    {
        dim3 grid(CC/64, NPIX/64);
        gemm_bf16_nt<64,64,true,false><<<grid, 256, 0, stream>>>(attn_out, proj_w, proj_b, out, NPIX, CC, CC);
    }
}

// Round 13
// 108.166 us; speedup vs baseline: 1.0994x; 1.0337x over previous
//
#include <hip/hip_runtime.h>
#include <hip/hip_bf16.h>

// Problem constants
#define BB 2
#define HH 56
#define WW 56
#define CC 256
#define HEADS 8
#define HD 32
#define KW 7
#define NPIX (BB*HH*WW)           // 6272
#define KV_N 512

using bf16x8 = __attribute__((ext_vector_type(8))) short;
using f32x4  = __attribute__((ext_vector_type(4))) float;

__device__ __forceinline__ ushort f2bf(float f) {
    union { float f; uint u; } v; v.f = f;
    uint r = v.u + 0x7FFF + ((v.u >> 16) & 1);   // round-to-nearest-even
    return (ushort)(r >> 16);
}
__device__ __forceinline__ float bf2f(ushort h) {
    union { uint u; float f; } v; v.u = ((uint)h) << 16;
    return v.f;
}
// quad butterfly add via DPP (pure VALU).
template<int CTRL>
__device__ __forceinline__ float dpp_qadd(float v) {
    union { float f; int i; } a, b;
    a.f = v;
    b.i = __builtin_amdgcn_update_dpp(0, a.i, CTRL, 0xF, 0xF, true);
    return v + b.f;
}

// ---- bulk f32 -> bf16 conversion (x, kv_w, proj_w), 8 elems/thread ----
__global__ __launch_bounds__(256) void cvt_to_bf16(
    const float* __restrict__ a, int na8,
    const float* __restrict__ b, int nb8,
    const float* __restrict__ c, int nc8,
    ushort* __restrict__ oa, ushort* __restrict__ ob, ushort* __restrict__ oc)
{
    const int t = blockIdx.x * 256 + threadIdx.x;
    const float* src; ushort* dst; int off;
    if (t < na8)             { src = a; dst = oa; off = t; }
    else if (t < na8 + nb8)  { src = b; dst = ob; off = t - na8; }
    else if (t < na8+nb8+nc8){ src = c; dst = oc; off = t - na8 - nb8; }
    else return;
    float4 f0 = *(const float4*)(src + (size_t)off * 8);
    float4 f1 = *(const float4*)(src + (size_t)off * 8 + 4);
    bf16x8 v;
    v[0]=f2bf(f0.x); v[1]=f2bf(f0.y); v[2]=f2bf(f0.z); v[3]=f2bf(f0.w);
    v[4]=f2bf(f1.x); v[5]=f2bf(f1.y); v[6]=f2bf(f1.z); v[7]=f2bf(f1.w);
    *(bf16x8*)(dst + (size_t)off * 8) = v;
}

// ---- bf16 MFMA GEMM: C[M][N] = A[M][K] @ Wt[N][K]^T + bias[N] ----
// Both operands pre-converted bf16 -> staging is pure bf16x8 copy.
template<int BM, int BN, bool OUT_BF16>
__global__ __launch_bounds__(256) void gemm_bf16_nt(
    const ushort* __restrict__ A, const ushort* __restrict__ Wt,
    const float* __restrict__ bias, void* __restrict__ Cv,
    int M, int N, int Kd)
{
    constexpr int BK  = 64;
    constexpr int LDT = 72;
    constexpr int WTM = BM / 2, WTN = BN / 2;
    constexpr int MF  = WTM / 16, NF = WTN / 16;

    __shared__ ushort As[BM][LDT];
    __shared__ ushort Bs[BN][LDT];

    const int tid  = threadIdx.x;
    const int lane = tid & 63;
    const int wid  = tid >> 6;
    const int wm   = wid >> 1;
    const int wn   = wid & 1;
    const int bm   = blockIdx.y * BM;
    const int bn   = blockIdx.x * BN;

    const int srow = tid >> 3;
    const int skq  = (tid & 7) * 8;

    f32x4 acc[MF][NF] = {};

    for (int k0 = 0; k0 < Kd; k0 += BK) {
        #pragma unroll
        for (int p = 0; p < BM / 32; ++p) {
            const int r = p * 32 + srow;
            *(bf16x8*)&As[r][skq] =
                *(const bf16x8*)(A + (size_t)(bm + r) * Kd + k0 + skq);
        }
        #pragma unroll
        for (int p = 0; p < BN / 32; ++p) {
            const int r = p * 32 + srow;
            *(bf16x8*)&Bs[r][skq] =
                *(const bf16x8*)(Wt + (size_t)(bn + r) * Kd + k0 + skq);
        }
        __syncthreads();

        #pragma unroll
        for (int ks = 0; ks < 2; ++ks) {
            const int koff = ks * 32 + (lane >> 4) * 8;
            bf16x8 af[MF], bf[NF];
            #pragma unroll
            for (int m = 0; m < MF; ++m)
                af[m] = *(const bf16x8*)&As[wm*WTM + m*16 + (lane & 15)][koff];
            #pragma unroll
            for (int n = 0; n < NF; ++n)
                bf[n] = *(const bf16x8*)&Bs[wn*WTN + n*16 + (lane & 15)][koff];
            #pragma unroll
            for (int m = 0; m < MF; ++m)
                #pragma unroll
                for (int n = 0; n < NF; ++n)
                    acc[m][n] = __builtin_amdgcn_mfma_f32_16x16x32_bf16(af[m], bf[n], acc[m][n], 0, 0, 0);
        }
        __syncthreads();
    }

    #pragma unroll
    for (int n = 0; n < NF; ++n) {
        const int col = bn + wn*WTN + n*16 + (lane & 15);
        const float bval = bias[col];
        #pragma unroll
        for (int m = 0; m < MF; ++m) {
            const int row0 = bm + wm*WTM + m*16 + (lane >> 4) * 4;
            #pragma unroll
            for (int r = 0; r < 4; ++r) {
                const float o = acc[m][n][r] + bval;
                if constexpr (OUT_BF16)
                    ((ushort*)Cv)[(size_t)(row0 + r) * N + col] = f2bf(o);
                else
                    ((float*)Cv)[(size_t)(row0 + r) * N + col] = o;
            }
        }
    }
}

// ---- Neighborhood attention, LDS-tiled, bf16 LDS, 8x4 tiles, row-split ----
// Block = (batch, 8x4 pixel tile, head), 256 threads, grid 1568.
// Thread = (pixel, 8-dim sub, row-half). No-max softmax (scores tiny; clamp 70
// for safety); phantom rows score -3.4e38 -> exp 0. Quad DPP reduce; cross-half
// combine via __shfl_xor(,4). Rule #20: compile-time indexing throughout.
#define TI_H 8
#define TJ_W 4
#define WIN_R 14
#define WIN_C 10
#define NWPIX (WIN_R*WIN_C)   // 140
#define LSTR 40
__global__ __launch_bounds__(256) void natt_tile(
    const float* __restrict__ q_extra, const ushort* __restrict__ kv,
    const float* __restrict__ rpb, ushort* __restrict__ attn_out)
{
    __shared__ ushort Ks[NWPIX * LSTR];   // 11.2 KB
    __shared__ ushort Vs[NWPIX * LSTR];   // 11.2 KB
    __shared__ float  Bias[169];

    const int blk  = blockIdx.x;
    const int head = blk & 7;
    const int t    = blk >> 3;          // 0..195
    const int tj   = t % 14;
    const int ti   = (t / 14) % 7;
    const int b    = t / 98;

    const int r0 = max(0, ti * TI_H - 3);
    const int c0 = max(0, tj * TJ_W - 3);

    const int tid = threadIdx.x;

    for (int e = tid; e < 169; e += 256)
        Bias[e] = rpb[head * 169 + e];

    for (int e = tid; e < NWPIX * 8; e += 256) {
        const int spix  = e >> 3;
        const int f4    = e & 7;
        const int kvh   = f4 >> 2;
        const int chunk = f4 & 3;
        const int wr   = spix / WIN_C;
        const int wc   = spix - wr * WIN_C;
        const int gr   = min(r0 + wr, HH - 1);
        const int gc   = min(c0 + wc, WW - 1);
        const ushort* src = kv + ((size_t)((b * HH + gr) * WW + gc)) * KV_N
                               + kvh * CC + head * HD + chunk * 8;
        ushort* dst = (kvh ? Vs : Ks) + spix * LSTR + chunk * 8;
        *(bf16x8*)dst = *(const bf16x8*)src;
    }

    const int sub  = tid & 3;
    const int half = (tid >> 2) & 1;
    const int p    = tid >> 3;          // 0..31
    const int li   = p >> 2, lj = p & 3;
    const int i = ti * TI_H + li, j = tj * TJ_W + lj;
    const int pix = (b * HH + i) * WW + j;
    const int d0 = sub * 8;

    const float scale = 0.17677669529663687f;  // 32^-0.5
    float q[8];
    {
        const float* qp = q_extra + (size_t)pix * CC + head * HD + d0;
        float4 v0 = *(const float4*)(qp);
        float4 v1 = *(const float4*)(qp + 4);
        q[0]=v0.x*scale; q[1]=v0.y*scale; q[2]=v0.z*scale; q[3]=v0.w*scale;
        q[4]=v1.x*scale; q[5]=v1.y*scale; q[6]=v1.z*scale; q[7]=v1.w*scale;
    }

    const int sh = min(max(i - 3, 0), HH - KW);
    const int sw = min(max(j - 3, 0), WW - KW);
    const int wr0 = sh - r0;            // 0..7
    const int wc0 = sw - c0;            // 0..3
    const int pbi0 = sh - i + 6;
    const int pbj0 = sw - j + 6;

    __syncthreads();

    // QK + bias over this half's 4 (padded) rows; no-max softmax
    float s[28];
    #pragma unroll
    for (int r = 0; r < 4; ++r) {
        const int a = min(half * 4 + r, 6);          // h1 r3 clamps to row 6
        const bool live = (half == 0) || (r < 3);    // h1 r3 is a phantom
        const ushort* kr = &Ks[((wr0 + a) * WIN_C + wc0) * LSTR + d0];
        const float* bp = &Bias[(pbi0 + a) * 13 + pbj0];
        #pragma unroll
        for (int c = 0; c < KW; ++c) {
            bf16x8 kk = *(const bf16x8*)(kr + c * LSTR);
            float v = q[0]*bf2f((ushort)kk[0]) + q[1]*bf2f((ushort)kk[1])
                    + q[2]*bf2f((ushort)kk[2]) + q[3]*bf2f((ushort)kk[3])
                    + q[4]*bf2f((ushort)kk[4]) + q[5]*bf2f((ushort)kk[5])
                    + q[6]*bf2f((ushort)kk[6]) + q[7]*bf2f((ushort)kk[7]);
            v = dpp_qadd<0xB1>(v);      // quad_perm xor 1
            v = dpp_qadd<0x4E>(v);      // quad_perm xor 2
            v += bp[c];
            s[r * KW + c] = live ? v : -3.4e38f;
        }
    }

    float sum = 0.f;
    #pragma unroll
    for (int k = 0; k < 28; ++k) {
        s[k] = __expf(fminf(s[k], 70.0f));
        sum += s[k];
    }
    sum += __shfl_xor(sum, 4);
    const float inv = 1.0f / sum;

    // PV over this half's rows (phantom row has zero weights)
    float acc[8] = {};
    #pragma unroll
    for (int r = 0; r < 4; ++r) {
        const int a = min(half * 4 + r, 6);
        const ushort* vr = &Vs[((wr0 + a) * WIN_C + wc0) * LSTR + d0];
        #pragma unroll
        for (int c = 0; c < KW; ++c) {
            bf16x8 vv = *(const bf16x8*)(vr + c * LSTR);
            const float w = s[r * KW + c];
            acc[0] += w*bf2f((ushort)vv[0]); acc[1] += w*bf2f((ushort)vv[1]);
            acc[2] += w*bf2f((ushort)vv[2]); acc[3] += w*bf2f((ushort)vv[3]);
            acc[4] += w*bf2f((ushort)vv[4]); acc[5] += w*bf2f((ushort)vv[5]);
            acc[6] += w*bf2f((ushort)vv[6]); acc[7] += w*bf2f((ushort)vv[7]);
        }
    }
    #pragma unroll
    for (int d = 0; d < 8; ++d)
        acc[d] += __shfl_xor(acc[d], 4);

    if (half == 0) {
        ushort* op = attn_out + (size_t)pix * CC + head * HD + d0;
        bf16x8 o;
        o[0]=f2bf(acc[0]*inv); o[1]=f2bf(acc[1]*inv);
        o[2]=f2bf(acc[2]*inv); o[3]=f2bf(acc[3]*inv);
        o[4]=f2bf(acc[4]*inv); o[5]=f2bf(acc[5]*inv);
        o[6]=f2bf(acc[6]*inv); o[7]=f2bf(acc[7]*inv);
        *(bf16x8*)op = o;
    }
}

extern "C" void kernel_launch(void* const* d_in, const int* in_sizes, int n_in,
                              void* d_out, int out_size, void* d_ws, size_t ws_size,
                              hipStream_t stream) {
    const float* x       = (const float*)d_in[0];
    const float* q_extra = (const float*)d_in[1];
    const float* kv_w    = (const float*)d_in[2];
    const float* kv_b    = (const float*)d_in[3];
    const float* rpb     = (const float*)d_in[4];
    const float* proj_w  = (const float*)d_in[5];
    const float* proj_b  = (const float*)d_in[6];
    float* out = (float*)d_out;

    // ws layout (all bf16)
    ushort* xbf   = (ushort*)d_ws;                         // NPIX*CC
    ushort* kvwbf = xbf + (size_t)NPIX * CC;               // 512*256
    ushort* pwbf  = kvwbf + (size_t)KV_N * CC;             // 256*256
    ushort* kv    = pwbf + (size_t)CC * CC;                // NPIX*512
    ushort* attn  = kv + (size_t)NPIX * KV_N;              // NPIX*256

    // 0) pre-convert x, kv_w, proj_w to bf16
    {
        const int na8 = NPIX * CC / 8;        // 200704
        const int nb8 = KV_N * CC / 8;        // 16384
        const int nc8 = CC * CC / 8;          // 8192
        const int tot = na8 + nb8 + nc8;      // 225280
        cvt_to_bf16<<<(tot + 255) / 256, 256, 0, stream>>>(
            x, na8, kv_w, nb8, proj_w, nc8, xbf, kvwbf, pwbf);
    }
    // 1) kv = bf16( xbf @ kvwbf^T + kv_b )   (M=6272, N=512, K=256)
    {
        dim3 grid(KV_N/64, NPIX/64);
        gemm_bf16_nt<64,64,true><<<grid, 256, 0, stream>>>(xbf, kvwbf, kv_b, kv, NPIX, KV_N, CC);
    }
    // 2) neighborhood attention
    {
        dim3 grid(BB * 7 * 14 * HEADS);
        natt_tile<<<grid, 256, 0, stream>>>(q_extra, kv, rpb, attn);
    }
    // 3) out = attn @ pwbf^T + proj_b   (M=6272, N=256, K=256)
    {
        dim3 grid(CC/64, NPIX/64);
        gemm_bf16_nt<64,64,false><<<grid, 256, 0, stream>>>(attn, pwbf, proj_b, out, NPIX, CC, CC);
    }
}